// Round 7
// baseline (301.432 us; speedup 1.0000x reference)
//
#include <hip/hip_runtime.h>

#define U_   2048
#define T_   200
#define S_   10
#define K_   20
#define H_   16
#define DU_  32
#define DE_  32
#define DIN_ 264   // 32 + 11 + 220 + 1

// ---------------- k_pre_f geometry ----------------
#define TPOS   64      // positions per tile
#define GR     50      // 16B granules per position row (800B)
#define GRP    56      // padded row stride in granules (XOR-swizzle space)
#define NSTW   7       // staging instrs per wave (56 total / 8 waves)
#define NBLK   256     // grid-resident blocks (1 per CU)
#define NITER  25      // 409600/64/256

__device__ __forceinline__ void g2l16(const void* g, void* l) {
    __builtin_amdgcn_global_load_lds(
        (const __attribute__((address_space(1))) void*)g,
        (__attribute__((address_space(3))) void*)l, 16, 0, 0);
}

// ---------------------------------------------------------------------------
// Kernel 1a: pre[pos,h] = f[pos,:] . Wx[43:243,h]   (f-part only, no bias)
// Grid-resident (256 blocks x 512 thr), each block streams 25 tiles of 64
// positions. LDS tile = padded/swizzled image of a contiguous 51200B f-chunk;
// global_load_lds sources are byte-linear => DRAM-friendly order. Double
// buffer + counted vmcnt(7): staging of tile i+1 stays in flight across the
// whole compute of tile i (never drained mid-loop). 8 waves = 8 column
// slices; cross-wave reduce through a padded LDS scratch. Weights via
// wave-uniform s_loads (R4-proven).
// ---------------------------------------------------------------------------
__global__ __launch_bounds__(512, 2) void k_pre_f(
    const float* __restrict__ f, const float* __restrict__ Wx,
    float* __restrict__ pre)
{
    __shared__ __align__(16) char fbuf[2][TPOS * GRP * 16];  // 2 x 57344 B
    __shared__ __align__(16) char red[TPOS * 33 * 16];       // 33792 B
    const int t    = threadIdx.x;
    const int lane = t & 63;
    const int w    = t >> 6;                 // wave id = column slice id
    const int b    = blockIdx.x;

    // slice w: granules [jbase, jbase+jcnt): w0,w1 -> 7; w2..7 -> 6  (sum 50)
    const int jbase = w * 6 + (w < 2 ? w : 2);
    const int jcnt  = (w < 2) ? 7 : 6;

    // Staging map: instr m (0..6) of wave w covers slots sp = t + 512*m.
    // Slot sp holds granule (p = sp/56, j = (sp%56) ^ (p&7)); read side uses
    // the same XOR -> ds_read_b128 at bank floor. Source offset precomputed.
    int srcoff[NSTW];
#pragma unroll
    for (int m = 0; m < NSTW; ++m) {
        const unsigned sp = (unsigned)(t + 512 * m);
        const unsigned p  = sp / GRP;
        unsigned j = (sp - p * GRP) ^ (p & 7u);
        if (j >= GR) j = 0;                  // pad slot: duplicate granule 0 (unread)
        srcoff[m] = (int)(p * 800u + j * 16u);
    }

    const char* fB = (const char*)f;
    const int pp = lane & 7;                 // read-side XOR key
    const int rp = t >> 3;                   // reduce: position 0..63
    const int hp = t & 7;                    // reduce: h-pair 0..7

    // ---- prologue: stage tile b into buf0 ----
    {
        const char* src = fB + (size_t)b * 51200;
        char* dst = (char*)fbuf[0];
#pragma unroll
        for (int m = 0; m < NSTW; ++m)
            g2l16(src + srcoff[m], dst + (size_t)(t + 512 * m) * 16);
    }

#pragma unroll 1
    for (int i = 0; i < NITER; ++i) {
        const int cur = i & 1;
        // -- 1. issue staging for tile i+1 (stays in flight across compute) --
        if (i + 1 < NITER) {
            const char* src = fB + (size_t)((i + 1) * NBLK + b) * 51200;
            char* dst = (char*)fbuf[cur ^ 1];
#pragma unroll
            for (int m = 0; m < NSTW; ++m)
                g2l16(src + srcoff[m], dst + (size_t)(t + 512 * m) * 16);
        }
        __builtin_amdgcn_sched_barrier(0);
        // -- 2. wait ONLY tile i's staging (7 new g2l16 + <=1 old store newer) --
        if (i + 1 < NITER) asm volatile("s_waitcnt vmcnt(7)" ::: "memory");
        else               asm volatile("s_waitcnt vmcnt(0)" ::: "memory");
        __builtin_amdgcn_s_barrier();
        __builtin_amdgcn_sched_barrier(0);

        // -- 3. slice compute: acc[16] over jcnt granules --
        const char* fb = (const char*)fbuf[cur];
        float acc[H_];
#pragma unroll
        for (int h = 0; h < H_; ++h) acc[h] = 0.f;
#pragma unroll
        for (int k = 0; k < 7; ++k) {
            if (k < jcnt) {                          // wave-uniform guard
                const int j = jbase + k;
                const int slot = lane * GRP + (j ^ pp);
                const float4 v = *(const float4*)(fb + (size_t)slot * 16);
                const float* wt = Wx + (43 + 4 * j) * H_;   // uniform -> s_load
#pragma unroll
                for (int h = 0; h < H_; ++h)
                    acc[h] += v.x * wt[h] + v.y * wt[h + 16]
                            + v.z * wt[h + 32] + v.w * wt[h + 48];
            }
        }

        // -- 4. write slice partials to red[pos][slice][16] (stride 33 f4) --
        {
            char* rb = red + (size_t)(lane * 33 + w * 4) * 16;
            *(float4*)(rb +  0) = make_float4(acc[0],  acc[1],  acc[2],  acc[3]);
            *(float4*)(rb + 16) = make_float4(acc[4],  acc[5],  acc[6],  acc[7]);
            *(float4*)(rb + 32) = make_float4(acc[8],  acc[9],  acc[10], acc[11]);
            *(float4*)(rb + 48) = make_float4(acc[12], acc[13], acc[14], acc[15]);
        }
        asm volatile("s_waitcnt lgkmcnt(0)" ::: "memory");
        __builtin_amdgcn_s_barrier();
        __builtin_amdgcn_sched_barrier(0);

        // -- 5. reduce 8 slices, store float2 per thread (1 store/wave/iter) --
        {
            float sx = 0.f, sy = 0.f;
#pragma unroll
            for (int o = 0; o < 8; ++o) {
                const float2 v = *(const float2*)(red + (size_t)(rp * 33 + o * 4) * 16 + hp * 8);
                sx += v.x; sy += v.y;
            }
            const int tile = i * NBLK + b;
            *(float2*)(pre + ((size_t)tile * TPOS + rp) * H_ + hp * 2) = make_float2(sx, sy);
        }
        // next iter's top barrier protects red/fbuf reuse
    }
}

// ---------------------------------------------------------------------------
// Kernel 1b: pre[pos,h] += b_rnn[h] + emb/q/ct parts (rows 0..42, 263).
// Thread-per-position; q/ct/did are <=40B-stride (line-dense); emb gather is
// L2/L3-served; pre RMW is L2-hot. Weights via wave-uniform s_loads.
// ---------------------------------------------------------------------------
__global__ __launch_bounds__(256) void k_emb(
    const float* __restrict__ q, const int* __restrict__ docid,
    const float* __restrict__ ct, const float* __restrict__ emb,
    const float* __restrict__ Wx, const float* __restrict__ brnn,
    float* __restrict__ pre)
{
    const int idx = blockIdx.x * 256 + threadIdx.x;   // 1600 blocks exact

    float acc[H_];
#pragma unroll
    for (int h = 0; h < H_; ++h) acc[h] = brnn[h];    // uniform -> s_load

    // emb part: Wx rows 0..31
    {
        const float4* e4 = (const float4*)(emb + (size_t)docid[idx] * DE_);
#pragma unroll
        for (int r = 0; r < DE_ / 4; ++r) {
            const float4 v = e4[r];
            const float* wt = Wx + (r * 4) * H_;
#pragma unroll
            for (int h = 0; h < H_; ++h)
                acc[h] += v.x * wt[h] + v.y * wt[h + 16] + v.z * wt[h + 32] + v.w * wt[h + 48];
        }
    }
    // q part: Wx rows 32..41
    {
        const float2* q2 = (const float2*)(q + (size_t)idx * S_);
#pragma unroll
        for (int r = 0; r < S_ / 2; ++r) {
            const float2 v = q2[r];
            const float* wt = Wx + (DE_ + 2 * r) * H_;
#pragma unroll
            for (int h = 0; h < H_; ++h)
                acc[h] += v.x * wt[h] + v.y * wt[h + 16];
        }
    }
    // ctime: Wx row 263
    {
        const float c = ct[idx];
        const float* wt = Wx + (DIN_ - 1) * H_;
#pragma unroll
        for (int h = 0; h < H_; ++h) acc[h] += c * wt[h];
    }

    // RMW into pre
    float4* o = (float4*)(pre + (size_t)idx * H_);
    float4 p0 = o[0], p1 = o[1], p2 = o[2], p3 = o[3];
    o[0] = make_float4(p0.x + acc[0],  p0.y + acc[1],  p0.z + acc[2],  p0.w + acc[3]);
    o[1] = make_float4(p1.x + acc[4],  p1.y + acc[5],  p1.z + acc[6],  p1.w + acc[7]);
    o[2] = make_float4(p2.x + acc[8],  p2.y + acc[9],  p2.z + acc[10], p2.w + acc[11]);
    o[3] = make_float4(p3.x + acc[12], p3.y + acc[13], p3.z + acc[14], p3.w + acc[15]);
}

// ---------------------------------------------------------------------------
// Kernel 2: sequential RNN scan per user (16 lanes = 16 h-components),
// fused LeakyReLU + Dense(32).  (unchanged)
// ---------------------------------------------------------------------------
__device__ __forceinline__ float tanh_fast(float x) {
    float e = __expf(2.f * x);
    return 1.f - 2.f / (e + 1.f);
}

__global__ __launch_bounds__(64) void k_rnn(
    const float* __restrict__ pre, const int* __restrict__ docid,
    const float* __restrict__ Wh, const float* __restrict__ Wd,
    const float* __restrict__ bd, float* __restrict__ out)
{
    const int tid = threadIdx.x;
    const int l = tid & 15;
    const int u = (blockIdx.x * 64 + tid) >> 4;

    const float* prow = pre + (size_t)u * T_ * H_;
    const int* drow = docid + (size_t)u * T_;

    float wh[16];
#pragma unroll
    for (int k = 0; k < 16; ++k) wh[k] = Wh[((l ^ k) << 4) | l];

    float h = 0.f;

    float pb0 = prow[0 * H_ + l], pb1 = prow[1 * H_ + l],
          pb2 = prow[2 * H_ + l], pb3 = prow[3 * H_ + l];
    int   m0 = drow[0], m1 = drow[1], m2 = drow[2], m3 = drow[3];

    for (int tb = 0; tb < T_; tb += 4) {
#pragma unroll
        for (int s = 0; s < 4; ++s) {
            float p; int m;
            if      (s == 0) { p = pb0; m = m0; }
            else if (s == 1) { p = pb1; m = m1; }
            else if (s == 2) { p = pb2; m = m2; }
            else             { p = pb3; m = m3; }

            int tn = tb + 4 + s; if (tn > T_ - 1) tn = T_ - 1;
            float pn = prow[tn * H_ + l];
            int   mn = drow[tn];
            if      (s == 0) { pb0 = pn; m0 = mn; }
            else if (s == 1) { pb1 = pn; m1 = mn; }
            else if (s == 2) { pb2 = pn; m2 = mn; }
            else             { pb3 = pn; m3 = mn; }

            float a0 = p, a1 = 0.f, a2 = 0.f, a3 = 0.f;
#pragma unroll
            for (int k = 0; k < 16; k += 4) {
                a0 += __shfl_xor(h, k + 0, 16) * wh[k + 0];
                a1 += __shfl_xor(h, k + 1, 16) * wh[k + 1];
                a2 += __shfl_xor(h, k + 2, 16) * wh[k + 2];
                a3 += __shfl_xor(h, k + 3, 16) * wh[k + 3];
            }
            float accv = (a0 + a1) + (a2 + a3);
            float th = tanh_fast(accv);
            h = (m != 0) ? th : h;
        }
    }

    float a = (h >= 0.f) ? h : 0.3f * h;

    float wd0[16], wd1[16];
#pragma unroll
    for (int k = 0; k < 16; ++k) {
        int j = l ^ k;
        wd0[k] = Wd[j * DU_ + l];
        wd1[k] = Wd[j * DU_ + l + 16];
    }
    float o0 = bd[l], o1 = bd[l + 16];
#pragma unroll
    for (int k = 0; k < 16; ++k) {
        float av = __shfl_xor(a, k, 16);
        o0 += av * wd0[k];
        o1 += av * wd1[k];
    }
    out[(size_t)u * DU_ + l] = o0;
    out[(size_t)u * DU_ + l + 16] = o1;
}

// ---------------------------------------------------------------------------
extern "C" void kernel_launch(void* const* d_in, const int* in_sizes, int n_in,
                              void* d_out, int out_size, void* d_ws, size_t ws_size,
                              hipStream_t stream) {
    const float* q     = (const float*)d_in[0];
    const float* f     = (const float*)d_in[1];
    const int*   docid = (const int*)  d_in[2];
    const float* ct    = (const float*)d_in[3];
    const float* emb   = (const float*)d_in[4];
    const float* Wx    = (const float*)d_in[5];
    const float* Wh    = (const float*)d_in[6];
    const float* brnn  = (const float*)d_in[7];
    const float* Wd    = (const float*)d_in[8];
    const float* bd    = (const float*)d_in[9];
    float* out = (float*)d_out;

    float* pre = (float*)d_ws;                   // U*T*H floats = 26.2 MB

    k_pre_f<<<NBLK, 512, 0, stream>>>(f, Wx, pre);
    k_emb<<<(U_ * T_) / 256, 256, 0, stream>>>(q, docid, ct, emb, Wx, brnn, pre);
    k_rnn<<<(U_ * H_) / 64, 64, 0, stream>>>(pre, docid, Wh, Wd, bd, out);
}

// Round 8
// 300.612 us; speedup vs baseline: 1.0027x; 1.0027x over previous
//
#include <hip/hip_runtime.h>

#define U_   2048
#define T_   200
#define S_   10
#define K_   20
#define H_   16
#define DU_  32
#define DE_  32
#define DIN_ 264   // 32 + 11 + 220 + 1

// ---------------- k_pre_f geometry ----------------
#define TPOS   64      // positions per tile
#define GR     50      // 16B granules per position row (800B)
#define GRP    56      // padded row stride in granules (XOR-swizzle space)
#define NSTW   7       // staging instrs per wave (56 total / 8 waves)
#define NBLK   256     // grid-resident blocks (1 per CU)
#define NITER  25      // 409600/64/256

__device__ __forceinline__ void g2l16(const void* g, void* l) {
    __builtin_amdgcn_global_load_lds(
        (const __attribute__((address_space(1))) void*)g,
        (__attribute__((address_space(3))) void*)l, 16, 0, 0);
}

// ---------------------------------------------------------------------------
// Kernel 1a: pre[pos,h] = f[pos,:] . Wx[43:243,h]   (f-part only, no bias)
// R7 structure, ONE change: the g2l16 LDS destination is now an explicitly
// WAVE-UNIFORM base (readfirstlane) — the HW takes the LDS dst from scalar
// M0 and writes base + lane*16 itself (m104). R7 passed a divergent VGPR
// pointer, which the compiler must scalarize (waterfall: 64 trips/instr) —
// the 10 us/iter we measured. Same byte layout, so correctness is identical.
// ---------------------------------------------------------------------------
__global__ __launch_bounds__(512, 2) void k_pre_f(
    const float* __restrict__ f, const float* __restrict__ Wx,
    float* __restrict__ pre)
{
    __shared__ __align__(16) char fbuf[2][TPOS * GRP * 16];  // 2 x 57344 B
    __shared__ __align__(16) char red[TPOS * 33 * 16];       // 33792 B
    const int t    = threadIdx.x;
    const int lane = t & 63;
    const int w    = t >> 6;                 // wave id = column slice id
    const int b    = blockIdx.x;

    // wave-uniform staging base: lane-0's t, forced into SGPR
    const int wbase = __builtin_amdgcn_readfirstlane(t & ~63);

    // slice w: granules [jbase, jbase+jcnt): w0,w1 -> 7; w2..7 -> 6  (sum 50)
    const int jbase = w * 6 + (w < 2 ? w : 2);
    const int jcnt  = (w < 2) ? 7 : 6;

    // Staging map: instr m of wave covers slots sp = t + 512*m (layout linear
    // in slot id). Slot sp holds granule (p = sp/56, j = (sp%56) ^ (p&7));
    // read side applies the same XOR. Per-lane SOURCE offset precomputed.
    int srcoff[NSTW];
#pragma unroll
    for (int m = 0; m < NSTW; ++m) {
        const unsigned sp = (unsigned)(t + 512 * m);
        const unsigned p  = sp / GRP;
        unsigned j = (sp - p * GRP) ^ (p & 7u);
        if (j >= GR) j = 0;                  // pad slot: duplicate granule 0 (unread)
        srcoff[m] = (int)(p * 800u + j * 16u);
    }

    const char* fB = (const char*)f;
    const int pp = lane & 7;                 // read-side XOR key
    const int rp = t >> 3;                   // reduce: position 0..63
    const int hp = t & 7;                    // reduce: h-pair 0..7

    // ---- prologue: stage tile b into buf0 ----
    {
        const char* src = fB + (size_t)b * 51200;
#pragma unroll
        for (int m = 0; m < NSTW; ++m)
            g2l16(src + srcoff[m],
                  (char*)fbuf[0] + (size_t)(wbase + 512 * m) * 16);  // uniform dst
    }

#pragma unroll 1
    for (int i = 0; i < NITER; ++i) {
        const int cur = i & 1;
        // -- 1. issue staging for tile i+1 (stays in flight across compute) --
        if (i + 1 < NITER) {
            const char* src = fB + (size_t)((i + 1) * NBLK + b) * 51200;
            char* dstb = (char*)fbuf[cur ^ 1];
#pragma unroll
            for (int m = 0; m < NSTW; ++m)
                g2l16(src + srcoff[m], dstb + (size_t)(wbase + 512 * m) * 16);
        }
        __builtin_amdgcn_sched_barrier(0);
        // -- 2. wait ONLY tile i's staging (7 old loads + 1 old store drain) --
        if (i + 1 < NITER) asm volatile("s_waitcnt vmcnt(7)" ::: "memory");
        else               asm volatile("s_waitcnt vmcnt(0)" ::: "memory");
        __builtin_amdgcn_s_barrier();
        __builtin_amdgcn_sched_barrier(0);

        // -- 3. slice compute: acc[16] over jcnt granules --
        const char* fb = (const char*)fbuf[cur];
        float acc[H_];
#pragma unroll
        for (int h = 0; h < H_; ++h) acc[h] = 0.f;
#pragma unroll
        for (int k = 0; k < 7; ++k) {
            if (k < jcnt) {                          // wave-uniform guard
                const int j = jbase + k;
                const int slot = lane * GRP + (j ^ pp);
                const float4 v = *(const float4*)(fb + (size_t)slot * 16);
                const float* wt = Wx + (43 + 4 * j) * H_;   // uniform -> s_load
#pragma unroll
                for (int h = 0; h < H_; ++h)
                    acc[h] += v.x * wt[h] + v.y * wt[h + 16]
                            + v.z * wt[h + 32] + v.w * wt[h + 48];
            }
        }

        // -- 4. write slice partials to red[pos][slice][16] (stride 33 f4) --
        {
            char* rb = red + (size_t)(lane * 33 + w * 4) * 16;
            *(float4*)(rb +  0) = make_float4(acc[0],  acc[1],  acc[2],  acc[3]);
            *(float4*)(rb + 16) = make_float4(acc[4],  acc[5],  acc[6],  acc[7]);
            *(float4*)(rb + 32) = make_float4(acc[8],  acc[9],  acc[10], acc[11]);
            *(float4*)(rb + 48) = make_float4(acc[12], acc[13], acc[14], acc[15]);
        }
        asm volatile("s_waitcnt lgkmcnt(0)" ::: "memory");
        __builtin_amdgcn_s_barrier();
        __builtin_amdgcn_sched_barrier(0);

        // -- 5. reduce 8 slices, store float2 per thread (coalesced 512B/wave) --
        {
            float sx = 0.f, sy = 0.f;
#pragma unroll
            for (int o = 0; o < 8; ++o) {
                const float2 v = *(const float2*)(red + (size_t)(rp * 33 + o * 4) * 16 + hp * 8);
                sx += v.x; sy += v.y;
            }
            const int tile = i * NBLK + b;
            *(float2*)(pre + ((size_t)tile * TPOS + rp) * H_ + hp * 2) = make_float2(sx, sy);
        }
        // next iter's barrier-after-vmcnt protects red/fbuf reuse
    }
}

// ---------------------------------------------------------------------------
// Kernel 1b: pre[pos,h] += b_rnn[h] + emb/q/ct parts (rows 0..42, 263).
// (unchanged from R7)
// ---------------------------------------------------------------------------
__global__ __launch_bounds__(256) void k_emb(
    const float* __restrict__ q, const int* __restrict__ docid,
    const float* __restrict__ ct, const float* __restrict__ emb,
    const float* __restrict__ Wx, const float* __restrict__ brnn,
    float* __restrict__ pre)
{
    const int idx = blockIdx.x * 256 + threadIdx.x;   // 1600 blocks exact

    float acc[H_];
#pragma unroll
    for (int h = 0; h < H_; ++h) acc[h] = brnn[h];    // uniform -> s_load

    {
        const float4* e4 = (const float4*)(emb + (size_t)docid[idx] * DE_);
#pragma unroll
        for (int r = 0; r < DE_ / 4; ++r) {
            const float4 v = e4[r];
            const float* wt = Wx + (r * 4) * H_;
#pragma unroll
            for (int h = 0; h < H_; ++h)
                acc[h] += v.x * wt[h] + v.y * wt[h + 16] + v.z * wt[h + 32] + v.w * wt[h + 48];
        }
    }
    {
        const float2* q2 = (const float2*)(q + (size_t)idx * S_);
#pragma unroll
        for (int r = 0; r < S_ / 2; ++r) {
            const float2 v = q2[r];
            const float* wt = Wx + (DE_ + 2 * r) * H_;
#pragma unroll
            for (int h = 0; h < H_; ++h)
                acc[h] += v.x * wt[h] + v.y * wt[h + 16];
        }
    }
    {
        const float c = ct[idx];
        const float* wt = Wx + (DIN_ - 1) * H_;
#pragma unroll
        for (int h = 0; h < H_; ++h) acc[h] += c * wt[h];
    }

    float4* o = (float4*)(pre + (size_t)idx * H_);
    float4 p0 = o[0], p1 = o[1], p2 = o[2], p3 = o[3];
    o[0] = make_float4(p0.x + acc[0],  p0.y + acc[1],  p0.z + acc[2],  p0.w + acc[3]);
    o[1] = make_float4(p1.x + acc[4],  p1.y + acc[5],  p1.z + acc[6],  p1.w + acc[7]);
    o[2] = make_float4(p2.x + acc[8],  p2.y + acc[9],  p2.z + acc[10], p2.w + acc[11]);
    o[3] = make_float4(p3.x + acc[12], p3.y + acc[13], p3.z + acc[14], p3.w + acc[15]);
}

// ---------------------------------------------------------------------------
// Kernel 2: sequential RNN scan per user (16 lanes = 16 h-components),
// fused LeakyReLU + Dense(32).  (unchanged)
// ---------------------------------------------------------------------------
__device__ __forceinline__ float tanh_fast(float x) {
    float e = __expf(2.f * x);
    return 1.f - 2.f / (e + 1.f);
}

__global__ __launch_bounds__(64) void k_rnn(
    const float* __restrict__ pre, const int* __restrict__ docid,
    const float* __restrict__ Wh, const float* __restrict__ Wd,
    const float* __restrict__ bd, float* __restrict__ out)
{
    const int tid = threadIdx.x;
    const int l = tid & 15;
    const int u = (blockIdx.x * 64 + tid) >> 4;

    const float* prow = pre + (size_t)u * T_ * H_;
    const int* drow = docid + (size_t)u * T_;

    float wh[16];
#pragma unroll
    for (int k = 0; k < 16; ++k) wh[k] = Wh[((l ^ k) << 4) | l];

    float h = 0.f;

    float pb0 = prow[0 * H_ + l], pb1 = prow[1 * H_ + l],
          pb2 = prow[2 * H_ + l], pb3 = prow[3 * H_ + l];
    int   m0 = drow[0], m1 = drow[1], m2 = drow[2], m3 = drow[3];

    for (int tb = 0; tb < T_; tb += 4) {
#pragma unroll
        for (int s = 0; s < 4; ++s) {
            float p; int m;
            if      (s == 0) { p = pb0; m = m0; }
            else if (s == 1) { p = pb1; m = m1; }
            else if (s == 2) { p = pb2; m = m2; }
            else             { p = pb3; m = m3; }

            int tn = tb + 4 + s; if (tn > T_ - 1) tn = T_ - 1;
            float pn = prow[tn * H_ + l];
            int   mn = drow[tn];
            if      (s == 0) { pb0 = pn; m0 = mn; }
            else if (s == 1) { pb1 = pn; m1 = mn; }
            else if (s == 2) { pb2 = pn; m2 = mn; }
            else             { pb3 = pn; m3 = mn; }

            float a0 = p, a1 = 0.f, a2 = 0.f, a3 = 0.f;
#pragma unroll
            for (int k = 0; k < 16; k += 4) {
                a0 += __shfl_xor(h, k + 0, 16) * wh[k + 0];
                a1 += __shfl_xor(h, k + 1, 16) * wh[k + 1];
                a2 += __shfl_xor(h, k + 2, 16) * wh[k + 2];
                a3 += __shfl_xor(h, k + 3, 16) * wh[k + 3];
            }
            float accv = (a0 + a1) + (a2 + a3);
            float th = tanh_fast(accv);
            h = (m != 0) ? th : h;
        }
    }

    float a = (h >= 0.f) ? h : 0.3f * h;

    float wd0[16], wd1[16];
#pragma unroll
    for (int k = 0; k < 16; ++k) {
        int j = l ^ k;
        wd0[k] = Wd[j * DU_ + l];
        wd1[k] = Wd[j * DU_ + l + 16];
    }
    float o0 = bd[l], o1 = bd[l + 16];
#pragma unroll
    for (int k = 0; k < 16; ++k) {
        float av = __shfl_xor(a, k, 16);
        o0 += av * wd0[k];
        o1 += av * wd1[k];
    }
    out[(size_t)u * DU_ + l] = o0;
    out[(size_t)u * DU_ + l + 16] = o1;
}

// ---------------------------------------------------------------------------
extern "C" void kernel_launch(void* const* d_in, const int* in_sizes, int n_in,
                              void* d_out, int out_size, void* d_ws, size_t ws_size,
                              hipStream_t stream) {
    const float* q     = (const float*)d_in[0];
    const float* f     = (const float*)d_in[1];
    const int*   docid = (const int*)  d_in[2];
    const float* ct    = (const float*)d_in[3];
    const float* emb   = (const float*)d_in[4];
    const float* Wx    = (const float*)d_in[5];
    const float* Wh    = (const float*)d_in[6];
    const float* brnn  = (const float*)d_in[7];
    const float* Wd    = (const float*)d_in[8];
    const float* bd    = (const float*)d_in[9];
    float* out = (float*)d_out;

    float* pre = (float*)d_ws;                   // U*T*H floats = 26.2 MB

    k_pre_f<<<NBLK, 512, 0, stream>>>(f, Wx, pre);
    k_emb<<<(U_ * T_) / 256, 256, 0, stream>>>(q, docid, ct, emb, Wx, brnn, pre);
    k_rnn<<<(U_ * H_) / 64, 64, 0, stream>>>(pre, docid, Wh, Wd, bd, out);
}

// Round 9
// 210.887 us; speedup vs baseline: 1.4294x; 1.4255x over previous
//
#include <hip/hip_runtime.h>

#define U_   2048
#define T_   200
#define S_   10
#define K_   20
#define H_   16
#define DU_  32
#define DE_  32
#define DIN_ 264   // 32 + 11 + 220 + 1

// ---------------------------------------------------------------------------
// Kernel 1: pre[pos,h] = b_rnn[h] + x[pos,:] . Wx[:,h]
// R4 structure (thread-per-position, SGPR weights via wave-uniform addresses,
// zero LDS / barriers / shuffles), ONE lever: __launch_bounds__(256, 8)
// forces <=64 VGPR -> 8 waves/SIMD (2x R4's occupancy). Discriminates
// latency-bound (time halves) vs L2-reuse-bound (time unchanged).
// ---------------------------------------------------------------------------
__global__ __launch_bounds__(256, 8) void k_pre(
    const float* __restrict__ q, const float* __restrict__ f,
    const int* __restrict__ docid, const float* __restrict__ ct,
    const float* __restrict__ emb, const float* __restrict__ Wx,
    const float* __restrict__ brnn, float* __restrict__ pre)
{
    const int idx = blockIdx.x * 256 + threadIdx.x;   // 1600 blocks exact

    float acc[H_];
#pragma unroll
    for (int h = 0; h < H_; ++h) acc[h] = brnn[h];    // uniform -> s_load

    // ---- features part (bulk of HBM): Wx rows 43..242 ----
    {
        const float4* f4 = (const float4*)(f + (size_t)idx * (S_ * K_)); // 800B rows
#pragma unroll 2
        for (int r = 0; r < (S_ * K_) / 4; ++r) {
            float4 v = f4[r];
            const float* w = Wx + (DE_ + S_ + 1 + r * 4) * H_;   // uniform
#pragma unroll
            for (int h = 0; h < H_; ++h)
                acc[h] += v.x * w[h] + v.y * w[h + 16] + v.z * w[h + 32] + v.w * w[h + 48];
        }
    }

    // ---- embedding part: Wx rows 0..31 ----
    {
        const float4* e4 = (const float4*)(emb + (size_t)docid[idx] * DE_);
#pragma unroll 2
        for (int r = 0; r < DE_ / 4; ++r) {
            float4 v = e4[r];
            const float* w = Wx + (r * 4) * H_;                  // uniform
#pragma unroll
            for (int h = 0; h < H_; ++h)
                acc[h] += v.x * w[h] + v.y * w[h + 16] + v.z * w[h + 32] + v.w * w[h + 48];
        }
    }

    // ---- quality part: Wx rows 32..41 ----
    {
        const float2* q2 = (const float2*)(q + (size_t)idx * S_);
#pragma unroll
        for (int r = 0; r < S_ / 2; ++r) {
            float2 v = q2[r];
            const float* w = Wx + (DE_ + r * 2) * H_;            // uniform
#pragma unroll
            for (int h = 0; h < H_; ++h)
                acc[h] += v.x * w[h] + v.y * w[h + 16];
        }
    }

    // ---- ctime: Wx row 263 ----
    {
        float c = ct[idx];
        const float* w = Wx + (DIN_ - 1) * H_;                   // uniform
#pragma unroll
        for (int h = 0; h < H_; ++h) acc[h] += c * w[h];
    }

    float4* o = (float4*)(pre + (size_t)idx * H_);
    o[0] = make_float4(acc[0], acc[1], acc[2], acc[3]);
    o[1] = make_float4(acc[4], acc[5], acc[6], acc[7]);
    o[2] = make_float4(acc[8], acc[9], acc[10], acc[11]);
    o[3] = make_float4(acc[12], acc[13], acc[14], acc[15]);
}

// ---------------------------------------------------------------------------
// Kernel 2: sequential RNN scan per user (16 lanes = 16 h-components),
// fused LeakyReLU + Dense(32).  (unchanged)
// ---------------------------------------------------------------------------
__device__ __forceinline__ float tanh_fast(float x) {
    float e = __expf(2.f * x);
    return 1.f - 2.f / (e + 1.f);
}

__global__ __launch_bounds__(64) void k_rnn(
    const float* __restrict__ pre, const int* __restrict__ docid,
    const float* __restrict__ Wh, const float* __restrict__ Wd,
    const float* __restrict__ bd, float* __restrict__ out)
{
    const int tid = threadIdx.x;
    const int l = tid & 15;
    const int u = (blockIdx.x * 64 + tid) >> 4;

    const float* prow = pre + (size_t)u * T_ * H_;
    const int* drow = docid + (size_t)u * T_;

    float wh[16];
#pragma unroll
    for (int k = 0; k < 16; ++k) wh[k] = Wh[((l ^ k) << 4) | l];

    float h = 0.f;

    float pb0 = prow[0 * H_ + l], pb1 = prow[1 * H_ + l],
          pb2 = prow[2 * H_ + l], pb3 = prow[3 * H_ + l];
    int   m0 = drow[0], m1 = drow[1], m2 = drow[2], m3 = drow[3];

    for (int tb = 0; tb < T_; tb += 4) {
#pragma unroll
        for (int s = 0; s < 4; ++s) {
            float p; int m;
            if      (s == 0) { p = pb0; m = m0; }
            else if (s == 1) { p = pb1; m = m1; }
            else if (s == 2) { p = pb2; m = m2; }
            else             { p = pb3; m = m3; }

            int tn = tb + 4 + s; if (tn > T_ - 1) tn = T_ - 1;
            float pn = prow[tn * H_ + l];
            int   mn = drow[tn];
            if      (s == 0) { pb0 = pn; m0 = mn; }
            else if (s == 1) { pb1 = pn; m1 = mn; }
            else if (s == 2) { pb2 = pn; m2 = mn; }
            else             { pb3 = pn; m3 = mn; }

            float a0 = p, a1 = 0.f, a2 = 0.f, a3 = 0.f;
#pragma unroll
            for (int k = 0; k < 16; k += 4) {
                a0 += __shfl_xor(h, k + 0, 16) * wh[k + 0];
                a1 += __shfl_xor(h, k + 1, 16) * wh[k + 1];
                a2 += __shfl_xor(h, k + 2, 16) * wh[k + 2];
                a3 += __shfl_xor(h, k + 3, 16) * wh[k + 3];
            }
            float accv = (a0 + a1) + (a2 + a3);
            float th = tanh_fast(accv);
            h = (m != 0) ? th : h;
        }
    }

    float a = (h >= 0.f) ? h : 0.3f * h;

    float wd0[16], wd1[16];
#pragma unroll
    for (int k = 0; k < 16; ++k) {
        int j = l ^ k;
        wd0[k] = Wd[j * DU_ + l];
        wd1[k] = Wd[j * DU_ + l + 16];
    }
    float o0 = bd[l], o1 = bd[l + 16];
#pragma unroll
    for (int k = 0; k < 16; ++k) {
        float av = __shfl_xor(a, k, 16);
        o0 += av * wd0[k];
        o1 += av * wd1[k];
    }
    out[(size_t)u * DU_ + l] = o0;
    out[(size_t)u * DU_ + l + 16] = o1;
}

// ---------------------------------------------------------------------------
extern "C" void kernel_launch(void* const* d_in, const int* in_sizes, int n_in,
                              void* d_out, int out_size, void* d_ws, size_t ws_size,
                              hipStream_t stream) {
    const float* q     = (const float*)d_in[0];
    const float* f     = (const float*)d_in[1];
    const int*   docid = (const int*)  d_in[2];
    const float* ct    = (const float*)d_in[3];
    const float* emb   = (const float*)d_in[4];
    const float* Wx    = (const float*)d_in[5];
    const float* Wh    = (const float*)d_in[6];
    const float* brnn  = (const float*)d_in[7];
    const float* Wd    = (const float*)d_in[8];
    const float* bd    = (const float*)d_in[9];
    float* out = (float*)d_out;

    float* pre = (float*)d_ws;                   // U*T*H floats = 26.2 MB

    k_pre<<<(U_ * T_) / 256, 256, 0, stream>>>(q, f, docid, ct, emb, Wx, brnn, pre);
    k_rnn<<<(U_ * H_) / 64, 64, 0, stream>>>(pre, docid, Wh, Wd, bd, out);
}